// Round 9
// baseline (187.574 us; speedup 1.0000x reference)
//
#include <hip/hip_runtime.h>
#include <hip/hip_bf16.h>
#include <cstdint>

typedef unsigned short ushortT;
typedef __attribute__((ext_vector_type(8))) short short8;
typedef __attribute__((ext_vector_type(4))) float f32x4;
typedef __attribute__((ext_vector_type(4))) unsigned short ushort4v;

// ---------------- problem constants ----------------
static constexpr int Bn = 4, Cc = 48, Hh = 64, Wd = 64, HW = 4096;
static constexpr int HID = 96, NSET = 32, INTERC = 24, HEADS = 8, CPH = 6;

// ---------------- ws layout (float offsets) ----------------
static constexpr int FA    = 786432;    // t1 bf16 planar
static constexpr int FB    = 2359296;   // t2 bf16 planar
static constexpr int FC    = 3932160;   // x1g bf16 planar
static constexpr int FD    = 5505024;   // uf bf16 planar
static constexpr int FARAW = 7077888;   // araw bf16 planar
static constexpr int FATT  = 7471104;   // attn_t bf16 [p][32]
static constexpr int FGAP  = 8781824;   // 192 fp32
static constexpr int FSP   = 8782400;   // Sp partials fp32 (32bh x 2chunk x 48)
static constexpr int FW    = 8790000;   // 147200 fp32 weights
static constexpr int FATTB = 8937200;   // att_bf [p][32] bf16
static constexpr int FWT   = 9199344;   // Wt bf16 (KBA)
static constexpr int FSTAT = 9260784;   // LN stats float2[16384] (mu, rstd)
static constexpr int FHBF  = 10309360;  // h_bf [p][96] bf16
static constexpr int FWPW  = 11095792;  // Wpw [224][64] bf16
static constexpr int FWQK  = 11102960;  // Wqk [144][64] bf16
static constexpr int FWKP  = 11107568;  // Wkp [48][96] bf16
static constexpr int FWMP  = 11109872;  // Wmp [48][64] bf16
static constexpr int FQKVR = 11111424;  // qkvr bf16 planar
static constexpr int FQKV  = 13470720;  // qkv bf16 planar

// ---- weight offsets inside FW ----
static constexpr int W_N1W=0, W_N1B=48, W_N2W=96, W_N2B=144;
static constexpr int W_KDW1=192, W_KDW2=4800, W_KC1A=5664, W_KC1B=10272;
static constexpr int W_KPROJ=11136, W_C2AW=15744, W_C2AB=16176;
static constexpr int W_C2BW=16200, W_C2BB=16584, W_C211W=16616, W_C211B=18152;
static constexpr int W_KW=18184, W_KB=128776, W_ATTG=131848, W_GA1=131880;
static constexpr int W_TEMP=131976, W_QKVW=131984, W_QKVDW=138896, W_MPROJ=140192;
static constexpr int W_CA1W=142496, W_CA1B=144800, W_CA2W=144848, W_CA2B=147152;

__device__ __forceinline__ float b2f(ushortT u) {
    union { uint32_t i; float f; } v; v.i = ((uint32_t)u) << 16; return v.f;
}
__device__ __forceinline__ ushortT f2b(float f) {
    union { float f; uint32_t i; } v; v.f = f;
    uint32_t i = v.i;
    uint32_t lsb = (i >> 16) & 1u;
    i += 0x7fffu + lsb;
    return (ushortT)(i >> 16);
}
__device__ __forceinline__ int dtype_bf16(const uint32_t* n1w_raw) {
    return n1w_raw[0] == 0x3F803F80u;
}
__device__ __forceinline__ ushortT raw_bf(const void* p, int idx, int fl) {
    return fl ? ((const ushortT*)p)[idx] : f2b(((const float*)p)[idx]);
}
__device__ __forceinline__ float raw_f(const void* p, int idx, int fl) {
    return fl ? b2f(((const ushortT*)p)[idx]) : ((const float*)p)[idx];
}

// ---------------- prep: convert weights + gap + LN stats ----------------
struct ConvPack {
    const void* src[27];
    int dstoff[27];
    int n[27];
};
struct RawW {
    const void* kdw1; const void* kc1a; const void* c211w; const void* qkvw;
    const void* kproj; const void* mproj; const void* kw; const void* kb;
    const void* n1w; const void* n1b; const void* n2w; const void* n2b;
};

__global__ void __launch_bounds__(256) k_prep(ConvPack p, RawW rw, float* __restrict__ dst,
                       ushortT* __restrict__ Wt, ushortT* __restrict__ Wpw,
                       ushortT* __restrict__ Wqk, ushortT* __restrict__ Wkp,
                       ushortT* __restrict__ Wmp,
                       const void* __restrict__ x, float* __restrict__ gap,
                       float2* __restrict__ stats,
                       const uint32_t* __restrict__ n1w_raw) {
    int fl = dtype_bf16(n1w_raw);
    int y = blockIdx.y;
    if (y < 27) {
        int n = p.n[y];
        for (int i = blockIdx.x * 256 + threadIdx.x; i < n; i += 64 * 256) {
            dst[p.dstoff[y] + i] = raw_f(p.src[y], i, fl);
        }
    } else if (y == 27) {
        for (int u = blockIdx.x * 256 + threadIdx.x; u < 24 * 160 * 32; u += 64 * 256) {
            int n = u & 31;
            int rest = u >> 5;
            int r = rest % 160;
            int gr = rest / 160;
            ushortT out;
            if (r < 144) {
                int j = r >> 2, i = r & 3;
                out = raw_bf(rw.kw, n * 3456 + gr * 144 + i * 36 + j, fl);
            } else if (r < 148) {
                out = raw_bf(rw.kb, n * HID + gr * 4 + (r - 144), fl);
            } else out = 0;
            Wt[u] = out;
        }
    } else if (y == 28) {
        for (int u = blockIdx.x * 256 + threadIdx.x; u < 224 * 64; u += 64 * 256) {
            int co = u >> 6, c = u & 63;
            ushortT v = 0;
            if (c < 48) {
                if (co < 96)       v = raw_bf(rw.kdw1,  co * 48 + c, fl);
                else if (co < 192) v = raw_bf(rw.kc1a,  (co - 96) * 48 + c, fl);
                else               v = raw_bf(rw.c211w, (co - 192) * 48 + c, fl);
            }
            Wpw[u] = v;
        }
    } else if (y == 29) {
        for (int u = blockIdx.x * 256 + threadIdx.x; u < 144 * 64; u += 64 * 256) {
            int co = u >> 6, c = u & 63;
            Wqk[u] = (c < 48) ? raw_bf(rw.qkvw, co * 48 + c, fl) : (ushortT)0;
        }
    } else if (y == 30) {
        for (int u = blockIdx.x * 256 + threadIdx.x; u < 48 * 96; u += 64 * 256) {
            int co = u / 96, c = u % 96;
            Wkp[u] = raw_bf(rw.kproj, co * 96 + c, fl);
        }
    } else if (y == 31) {
        for (int u = blockIdx.x * 256 + threadIdx.x; u < 48 * 64; u += 64 * 256) {
            int co = u >> 6, c = u & 63;
            Wmp[u] = (c < 48) ? raw_bf(rw.mproj, co * 48 + c, fl) : (ushortT)0;
        }
    } else if (y == 32) {
        __shared__ float red[4];
        for (int bc = blockIdx.x; bc < Bn * Cc; bc += 64) {
            float s = 0.f;
            if (fl) {
                const ushortT* xb = (const ushortT*)x + bc * HW;
                for (int i = threadIdx.x; i < HW; i += 256) s += b2f(xb[i]);
            } else {
                const float* xb = (const float*)x + bc * HW;
                for (int i = threadIdx.x; i < HW; i += 256) s += xb[i];
            }
            #pragma unroll
            for (int o = 32; o > 0; o >>= 1) s += __shfl_down(s, o);
            int lane = threadIdx.x & 63, wv = threadIdx.x >> 6;
            if (lane == 0) red[wv] = s;
            __syncthreads();
            if (threadIdx.x == 0)
                gap[bc] = (red[0] + red[1] + red[2] + red[3]) * (1.f / HW);
            __syncthreads();
        }
    } else {
        // y = 33..36: LN stats only: 4 lanes per pixel, 12 ch each -> (mu, rstd)
        int slice = y - 33;
        int tid = threadIdx.x;
        int pp = slice * 4096 + blockIdx.x * 64 + (tid >> 2);
        int part = tid & 3;
        int b = pp >> 12, hw = pp & 4095;
        const ushortT* xbh = (const ushortT*)x + (size_t)b * Cc * HW + hw;
        const float*  xbf = (const float*)x + (size_t)b * Cc * HW + hw;
        float s = 0.f, ss = 0.f;
        #pragma unroll
        for (int j = 0; j < 12; j++) {
            int c = part * 12 + j;
            float t = fl ? b2f(xbh[c * HW]) : xbf[c * HW];
            s += t; ss += t * t;
        }
        s  += __shfl_xor(s, 1);  s  += __shfl_xor(s, 2);
        ss += __shfl_xor(ss, 1); ss += __shfl_xor(ss, 2);
        float mu = s * (1.f / Cc);
        float var = ss * (1.f / Cc) - mu * mu;
        float r = rsqrtf(var + 1e-6f);
        if (part == 0) {
            float2 o; o.x = mu; o.y = r;
            stats[pp] = o;
        }
    }
}

// 6-tap raw row loader (cols w0-1..w0+4, zero outside [0,64))
__device__ __forceinline__ void load6(const void* plane, int fl, int base, int w0, float* f) {
    if (fl) {
        const ushortT* rp = (const ushortT*)plane + base;
        ushort4v mm = *(const ushort4v*)rp;
        f[1] = b2f(mm[0]); f[2] = b2f(mm[1]); f[3] = b2f(mm[2]); f[4] = b2f(mm[3]);
        f[0] = (w0 > 0)  ? b2f(rp[-1]) : 0.f;
        f[5] = (w0 < 60) ? b2f(rp[4])  : 0.f;
    } else {
        const float* rp = (const float*)plane + base;
        float4 mm = *(const float4*)rp;
        f[1] = mm.x; f[2] = mm.y; f[3] = mm.z; f[4] = mm.w;
        f[0] = (w0 > 0)  ? rp[-1] : 0.f;
        f[5] = (w0 < 60) ? rp[4]  : 0.f;
    }
}

// 8-px depthwise 3x3 row accumulate: aa[0..7] += conv of rows h-1..h+1 at cols w0..w0+7
__device__ __forceinline__ void dwconv8(const ushortT* plane, const float* wk,
                                        int h, int w0, float* aa) {
    #pragma unroll
    for (int ki = 0; ki < 3; ki++) {
        int hh = h + ki - 1;
        if ((unsigned)hh < 64u) {
            const ushortT* row = plane + hh * 64 + w0;
            ushort4v v0 = *(const ushort4v*)row;
            ushort4v v1 = *(const ushort4v*)(row + 4);
            float f[10];
            f[0] = (w0 > 0)  ? b2f(row[-1]) : 0.f;
            f[1] = b2f(v0[0]); f[2] = b2f(v0[1]); f[3] = b2f(v0[2]); f[4] = b2f(v0[3]);
            f[5] = b2f(v1[0]); f[6] = b2f(v1[1]); f[7] = b2f(v1[2]); f[8] = b2f(v1[3]);
            f[9] = (w0 < 56) ? b2f(row[8])  : 0.f;
            float k0 = wk[ki * 3], k1 = wk[ki * 3 + 1], k2 = wk[ki * 3 + 2];
            #pragma unroll
            for (int i = 0; i < 8; i++)
                aa[i] += k0 * f[i] + k1 * f[i + 1] + k2 * f[i + 2];
        }
    }
}

// ---------------- pw1m: LN applied inline from stats. y=0 x<256: [224x48] -> t1,t2,attn_t ; y=0 x>=256: c2a->araw ; y=1 x<256: [144x48] -> qkvr ----------------
__global__ void __launch_bounds__(256) k_pw1m(const void* __restrict__ x, const float2* __restrict__ stats,
                       const ushortT* __restrict__ Wpw, const ushortT* __restrict__ Wqk,
                       RawW rw, const float* __restrict__ wts,
                       ushortT* __restrict__ t1, ushortT* __restrict__ t2,
                       ushortT* __restrict__ attn_t, ushortT* __restrict__ qkvr,
                       ushortT* __restrict__ araw,
                       const uint32_t* __restrict__ n1w_raw) {
    int fl = dtype_bf16(n1w_raw);
    if (blockIdx.x >= 256) {
        if (blockIdx.y != 0) return;
        // c2a grouped 3x3 conv with inline LN (n1) from stats
        int sub = blockIdx.x - 256;        // 0..383
        int o = sub >> 4;                  // 0..23
        int xb = sub & 15;
        int pbase = xb * 1024 + threadIdx.x * 4;
        int b = pbase >> 12, hw = pbase & 4095, h = hw >> 6, w0 = hw & 63;
        const float2* st = stats + b * 4096;
        float nw0 = raw_f(rw.n1w, 2 * o, fl),     nb0 = raw_f(rw.n1b, 2 * o, fl);
        float nw1 = raw_f(rw.n1w, 2 * o + 1, fl), nb1 = raw_f(rw.n1b, 2 * o + 1, fl);
        const void* pl0;
        const void* pl1;
        if (fl) {
            pl0 = (const void*)((const ushortT*)x + (size_t)(b * Cc + 2 * o) * HW);
            pl1 = (const void*)((const ushortT*)x + (size_t)(b * Cc + 2 * o + 1) * HW);
        } else {
            pl0 = (const void*)((const float*)x + (size_t)(b * Cc + 2 * o) * HW);
            pl1 = (const void*)((const float*)x + (size_t)(b * Cc + 2 * o + 1) * HW);
        }
        const float* wk = wts + W_C2AW + (o * 2) * 9;
        float bias = wts[W_C2AB + o];
        float a0 = bias, a1 = bias, a2 = bias, a3 = bias;
        #pragma unroll
        for (int ki = 0; ki < 3; ki++) {
            int hh = h + ki - 1;
            if ((unsigned)hh < 64u) {
                int base = hh * 64 + w0;
                float mu[6], rr[6];
                #pragma unroll
                for (int i = 0; i < 6; i++) {
                    int c = w0 + i - 1;
                    if ((unsigned)c < 64u) {
                        float2 s2 = st[hh * 64 + c];
                        mu[i] = s2.x; rr[i] = s2.y;
                    } else { mu[i] = 0.f; rr[i] = 0.f; }
                }
                float f[6], g[6];
                float k0a = wk[ki * 3], k1a = wk[ki * 3 + 1], k2a = wk[ki * 3 + 2];
                float k0b = wk[9 + ki * 3], k1b = wk[9 + ki * 3 + 1], k2b = wk[9 + ki * 3 + 2];
                // channel 2o
                load6(pl0, fl, base, w0, f);
                g[0] = (w0 > 0)  ? nw0 * ((f[0] - mu[0]) * rr[0]) + nb0 : 0.f;
                #pragma unroll
                for (int i = 1; i < 5; i++) g[i] = nw0 * ((f[i] - mu[i]) * rr[i]) + nb0;
                g[5] = (w0 < 60) ? nw0 * ((f[5] - mu[5]) * rr[5]) + nb0 : 0.f;
                a0 += k0a * g[0] + k1a * g[1] + k2a * g[2];
                a1 += k0a * g[1] + k1a * g[2] + k2a * g[3];
                a2 += k0a * g[2] + k1a * g[3] + k2a * g[4];
                a3 += k0a * g[3] + k1a * g[4] + k2a * g[5];
                // channel 2o+1
                load6(pl1, fl, base, w0, f);
                g[0] = (w0 > 0)  ? nw1 * ((f[0] - mu[0]) * rr[0]) + nb1 : 0.f;
                #pragma unroll
                for (int i = 1; i < 5; i++) g[i] = nw1 * ((f[i] - mu[i]) * rr[i]) + nb1;
                g[5] = (w0 < 60) ? nw1 * ((f[5] - mu[5]) * rr[5]) + nb1 : 0.f;
                a0 += k0b * g[0] + k1b * g[1] + k2b * g[2];
                a1 += k0b * g[1] + k1b * g[2] + k2b * g[3];
                a2 += k0b * g[2] + k1b * g[3] + k2b * g[4];
                a3 += k0b * g[3] + k1b * g[4] + k2b * g[5];
            }
        }
        ushort4v out;
        out[0] = f2b(a0); out[1] = f2b(a1); out[2] = f2b(a2); out[3] = f2b(a3);
        *(ushort4v*)(araw + (size_t)(b * INTERC + o) * HW + hw) = out;
        return;
    }

    // MFMA blocks: stage normalized bf16 fragments into LDS (bit-identical to old xnb/xmb)
    __shared__ ushortT xS[64][72];     // [pixel][ch], pad 72 -> 144B rows (16B aligned)
    int blk = blockIdx.x;
    int p0 = blk * 64;
    int b = p0 >> 12, hw0 = p0 & 4095;
    const float2* st = stats + b * 4096 + hw0;
    const void* nwp = blockIdx.y ? rw.n2w : rw.n1w;
    const void* nbp = blockIdx.y ? rw.n2b : rw.n1b;
    const ushortT* xh = (const ushortT*)x + (size_t)b * Cc * HW + hw0;
    const float*  xf = (const float*)x  + (size_t)b * Cc * HW + hw0;
    for (int i = threadIdx.x; i < 48 * 64; i += 256) {
        int ch = i >> 6, w = i & 63;
        float v = fl ? b2f(xh[(size_t)ch * HW + w]) : xf[(size_t)ch * HW + w];
        float2 s2 = st[w];
        float yv = (v - s2.x) * s2.y;
        xS[w][ch] = f2b(raw_f(nwp, ch, fl) * yv + raw_f(nbp, ch, fl));
    }
    for (int i = threadIdx.x; i < 16 * 64; i += 256) {
        int ch = 48 + (i >> 6), w = i & 63;
        xS[w][ch] = 0;
    }
    __syncthreads();

    int wave = threadIdx.x >> 6, lane = threadIdx.x & 63;
    int m = lane & 15, q = lane >> 4;
    int pl = wave * 16 + m;
    int p = p0 + pl;
    int hw = p & 4095;
    short8 B0 = *(const short8*)&xS[pl][q * 8];
    short8 B1 = *(const short8*)&xS[pl][32 + q * 8];
    if (blockIdx.y == 0) {
        #pragma unroll
        for (int t = 0; t < 14; t++) {
            short8 A0 = *(const short8*)(Wpw + (16 * t + m) * 64 + q * 8);
            short8 A1 = *(const short8*)(Wpw + (16 * t + m) * 64 + 32 + q * 8);
            f32x4 z = {0.f, 0.f, 0.f, 0.f};
            f32x4 D = __builtin_amdgcn_mfma_f32_16x16x32_bf16(A0, B0, z, 0, 0, 0);
            D = __builtin_amdgcn_mfma_f32_16x16x32_bf16(A1, B1, D, 0, 0, 0);
            #pragma unroll
            for (int g = 0; g < 4; g++) {
                int co = 16 * t + 4 * q + g;
                if (t < 6) t1[(size_t)(b * HID + co) * HW + hw] = f2b(D[g]);
                else if (t < 12) t2[(size_t)(b * HID + (co - 96)) * HW + hw] = f2b(D[g]);
                else {
                    int n = co - 192;
                    attn_t[(size_t)p * 32 + n] = f2b(D[g] + wts[W_C211B + n]);
                }
            }
        }
    } else {
        #pragma unroll
        for (int t = 0; t < 9; t++) {
            short8 A0 = *(const short8*)(Wqk + (16 * t + m) * 64 + q * 8);
            short8 A1 = *(const short8*)(Wqk + (16 * t + m) * 64 + 32 + q * 8);
            f32x4 z = {0.f, 0.f, 0.f, 0.f};
            f32x4 D = __builtin_amdgcn_mfma_f32_16x16x32_bf16(A0, B0, z, 0, 0, 0);
            D = __builtin_amdgcn_mfma_f32_16x16x32_bf16(A1, B1, D, 0, 0, 0);
            #pragma unroll
            for (int g = 0; g < 4; g++) {
                int co = 16 * t + 4 * q + g;
                qkvr[(size_t)(b * 144 + co) * HW + hw] = f2b(D[g]);
            }
        }
    }
}

// ---------------- dw: y<96 kdw2->gelu->x1g ; y<192 kc1b->uf ; y<336 qkvdw->qkv ; y<344 att-assembly->att_bf. grid (8, 344), 8 px/thread ----------------
__global__ void __launch_bounds__(256) k_dw(const ushortT* __restrict__ t1, const ushortT* __restrict__ t2,
                     const ushortT* __restrict__ qkvr, const ushortT* __restrict__ araw,
                     const ushortT* __restrict__ attn_t, const float* __restrict__ wts,
                     ushortT* __restrict__ x1g, ushortT* __restrict__ uf,
                     ushortT* __restrict__ qkv, ushortT* __restrict__ att_bf) {
    int y = blockIdx.y;

    if (y < 336) {
        int pbase = blockIdx.x * 2048 + threadIdx.x * 8;
        int b = pbase >> 12, hw = pbase & 4095, h = hw >> 6, w0 = hw & 63;
        const ushortT* plane;
        const float* wk;
        ushortT* dst;
        size_t idx;
        if (y < 96) {
            plane = t1 + (size_t)(b * HID + y) * HW;
            wk = wts + W_KDW2 + y * 9;
            dst = x1g; idx = (size_t)(b * HID + y) * HW + hw;
        } else if (y < 192) {
            int c = y - 96;
            plane = t2 + (size_t)(b * HID + c) * HW;
            wk = wts + W_KC1B + c * 9;
            dst = uf; idx = (size_t)(b * HID + c) * HW + hw;
        } else {
            int ch = y - 192;
            plane = qkvr + (size_t)(b * 144 + ch) * HW;
            wk = wts + W_QKVDW + ch * 9;
            dst = qkv; idx = (size_t)(b * 144 + ch) * HW + hw;
        }

        float aa[8];
        #pragma unroll
        for (int i = 0; i < 8; i++) aa[i] = 0.f;
        dwconv8(plane, wk, h, w0, aa);

        uint32_t pk[4];
        if (y < 96) {
            #pragma unroll
            for (int i = 0; i < 4; i++) {
                float g0 = 0.5f * aa[2*i]   * (1.f + erff(aa[2*i]   * 0.70710678118654752f));
                float g1 = 0.5f * aa[2*i+1] * (1.f + erff(aa[2*i+1] * 0.70710678118654752f));
                pk[i] = (uint32_t)f2b(g0) | ((uint32_t)f2b(g1) << 16);
            }
        } else {
            #pragma unroll
            for (int i = 0; i < 4; i++)
                pk[i] = (uint32_t)f2b(aa[2*i]) | ((uint32_t)f2b(aa[2*i+1]) << 16);
        }
        uint4 o; o.x = pk[0]; o.y = pk[1]; o.z = pk[2]; o.w = pk[3];
        *(uint4*)(dst + idx) = o;
    } else {
        // att-assembly: att = attgamma*c2b(SG(araw)) + attn_t -> att_bf (light, per-pixel)
        int p = ((y - 336) * 8 + blockIdx.x) * 256 + threadIdx.x;
        int b = p >> 12, hw = p & 4095;
        const ushortT* ab = araw + (size_t)b * INTERC * HW + hw;
        float sg[12];
        #pragma unroll
        for (int i = 0; i < 12; i++) sg[i] = b2f(ab[i * HW]) * b2f(ab[(12 + i) * HW]);
        const ushortT* ct = attn_t + (size_t)p * 32;
        uint32_t packed[16];
        #pragma unroll
        for (int nq = 0; nq < 16; nq++) {
            float v2[2];
            #pragma unroll
            for (int u = 0; u < 2; u++) {
                int n = nq * 2 + u;
                float a = wts[W_C2BB + n];
                #pragma unroll
                for (int c = 0; c < 12; c++) a += wts[W_C2BW + n * 12 + c] * sg[c];
                v2[u] = wts[W_ATTG + n] * a + b2f(ct[n]);
            }
            packed[nq] = (uint32_t)f2b(v2[0]) | ((uint32_t)f2b(v2[1]) << 16);
        }
        uint4* dst = (uint4*)(att_bf + (size_t)p * 32);
        #pragma unroll
        for (int qd = 0; qd < 4; qd++) {
            uint4 v; v.x = packed[qd*4]; v.y = packed[qd*4+1]; v.z = packed[qd*4+2]; v.w = packed[qd*4+3];
            dst[qd] = v;
        }
    }
}

// ---------------- kba (+smat): y<24 KBA core (LDS-staged taps) -> h_bf ; y==24 smat partials -> Sp. grid (64,25) x 256 ----------------
__global__ void __launch_bounds__(256) k_kba(const ushortT* __restrict__ att_bf, const ushortT* __restrict__ uf,
                     const ushortT* __restrict__ x1g, const ushortT* __restrict__ Wt,
                     const ushortT* __restrict__ qkv, const float* __restrict__ wts,
                     ushortT* __restrict__ h_bf, float* __restrict__ Sp) {
    __shared__ float red[48 * 4];
    __shared__ ushortT ufS[4][6][72];   // [ci][row h0-1..h0+4][col -1..64], pad 72
    if (blockIdx.y == 24) {
        int sub = blockIdx.x;               // 0..63
        int bh = sub >> 1, chunk = sub & 1;
        int b = bh / HEADS, hd = bh % HEADS;
        const ushortT* qb = qkv + (size_t)(b * 144 + hd * CPH) * HW;
        const ushortT* kb = qkv + (size_t)(b * 144 + 48 + hd * CPH) * HW;
        float acc[48];
        #pragma unroll
        for (int t = 0; t < 48; t++) acc[t] = 0.f;
        #pragma unroll
        for (int i = 0; i < 8; i++) {
            int px = chunk * 2048 + i * 256 + threadIdx.x;
            float qv[CPH], kv[CPH];
            #pragma unroll
            for (int c = 0; c < CPH; c++) { qv[c] = b2f(qb[c * HW + px]); kv[c] = b2f(kb[c * HW + px]); }
            #pragma unroll
            for (int c = 0; c < CPH; c++) {
                #pragma unroll
                for (int d = 0; d < CPH; d++) acc[c * CPH + d] += qv[c] * kv[d];
                acc[36 + c] += qv[c] * qv[c];
                acc[42 + c] += kv[c] * kv[c];
            }
        }
        int lane = threadIdx.x & 63, wv = threadIdx.x >> 6;
        #pragma unroll
        for (int t = 0; t < 48; t++) {
            float v = acc[t];
            #pragma unroll
            for (int o = 32; o > 0; o >>= 1) v += __shfl_down(v, o);
            if (lane == 0) red[t * 4 + wv] = v;
        }
        __syncthreads();
        if (threadIdx.x < 48)
            Sp[(bh * 2 + chunk) * 48 + threadIdx.x] =
                red[threadIdx.x * 4] + red[threadIdx.x * 4 + 1] +
                red[threadIdx.x * 4 + 2] + red[threadIdx.x * 4 + 3];
        return;
    }

    int wave = threadIdx.x >> 6, lane = threadIdx.x & 63;
    int m = lane & 15, q = lane >> 4;
    int gr = blockIdx.y;
    int b = blockIdx.x >> 4;            // block covers 256 consecutive pixels
    int h0 = (blockIdx.x & 15) * 4;     // rows h0..h0+3, wave handles row h0+wave

    // stage uf tile: 4 ch x 6 rows (h0-1..h0+4) x 66 cols (-1..64), halo = 0
    #pragma unroll
    for (int pr = 0; pr < 24; pr += 4) {
        int pp = pr + wave;
        int ci = pp / 6, r = pp % 6;
        int hh = h0 - 1 + r;
        ushortT v = 0;
        if ((unsigned)hh < 64u)
            v = uf[(size_t)(b * HID + gr * 4 + ci) * HW + hh * 64 + lane];
        ufS[ci][r][lane + 1] = v;
        if (lane < 2) ufS[ci][r][lane * 65] = 0;   // cols -1 and 64
    }

    short8 A[10];
    const ushortT* wtg = Wt + gr * 160 * 32;
    #pragma unroll
    for (int t = 0; t < 10; t++)
        A[t] = *(const short8*)(wtg + (16 * t + m) * 32 + q * 8);

    __syncthreads();

    for (int tile = 0; tile < 4; tile++) {
        int p = blockIdx.x * 256 + wave * 64 + tile * 16 + m;
        int hw = p & 4095, w = hw & 63;

        short8 Bf = *(const short8*)(att_bf + (size_t)p * 32 + q * 8);

        f32x4 D[10];
        #pragma unroll
        for (int t = 0; t < 10; t++) {
            f32x4 z = {0.f, 0.f, 0.f, 0.f};
            D[t] = __builtin_amdgcn_mfma_f32_16x16x32_bf16(A[t], Bf, z, 0, 0, 0);
        }

        float s0 = 0.f, s1 = 0.f, s2 = 0.f, s3 = 0.f;
        #pragma unroll
        for (int t = 0; t < 9; t++) {
            int j = 4 * t + q;
            int ci = j / 9;
            int kk = j - 9 * ci;
            int ki = kk / 3, kj = kk - 3 * ki;
            float tap = b2f(ufS[ci][wave + ki][w + kj]);
            s0 += D[t][0] * tap;
            s1 += D[t][1] * tap;
            s2 += D[t][2] * tap;
            s3 += D[t][3] * tap;
        }
        s0 += D[9][0]; s1 += D[9][1]; s2 += D[9][2]; s3 += D[9][3];

        s0 += __shfl_xor(s0, 16); s0 += __shfl_xor(s0, 32);
        s1 += __shfl_xor(s1, 16); s1 += __shfl_xor(s1, 32);
        s2 += __shfl_xor(s2, 16); s2 += __shfl_xor(s2, 32);
        s3 += __shfl_xor(s3, 16); s3 += __shfl_xor(s3, 32);

        float sel = (q == 0) ? s0 : ((q == 1) ? s1 : ((q == 2) ? s2 : s3));
        int ch = gr * 4 + q;
        size_t idx = (size_t)(b * HID + ch) * HW + hw;
        float x2 = sel * wts[W_GA1 + ch] + b2f(ufS[q][wave + 1][w + 1]);
        float hv = b2f(x1g[idx]) * x2;
        h_bf[(size_t)p * 96 + ch] = f2b(hv);
    }
}

// ---------------- finalm: softmax(Sp)+ca in-block; v-tile LDS stage; kproj-MFMA + S@v + mproj-MFMA + residual. grid 256 x 256 ----------------
__global__ void __launch_bounds__(256) k_finalm(const void* __restrict__ x, const uint32_t* __restrict__ n1w_raw,
                        const ushortT* __restrict__ h_bf, const ushortT* __restrict__ Wkp,
                        const ushortT* __restrict__ Wmp, const ushortT* __restrict__ qkv,
                        const float* __restrict__ Sp, const float* __restrict__ gap,
                        const float* __restrict__ wts, void* __restrict__ out) {
    int fl = dtype_bf16(n1w_raw);
    int wave = threadIdx.x >> 6, lane = threadIdx.x & 63;
    int m = lane & 15, q = lane >> 4;
    int p = blockIdx.x * 64 + wave * 16 + m;
    int hw = p & 4095;
    int wl = wave * 16 + m;            // within-block pixel 0..63
    int bblk = (blockIdx.x * 64) >> 12;
    int hw0 = (blockIdx.x * 64) & 4095;

    __shared__ float sm[384];
    __shared__ float S_l[288];
    __shared__ float caL[96];
    __shared__ ushortT vS[48 * 68];    // v-tile, stride 68 to spread banks

    // stage v-tile: 48 channels x 64 pixels, coalesced rows
    for (int i2 = threadIdx.x; i2 < 48 * 64; i2 += 256) {
        int ch = i2 >> 6, w2 = i2 & 63;
        vS[ch * 68 + w2] = qkv[(size_t)(bblk * 144 + 96 + ch) * HW + hw0 + w2];
    }
    for (int i = threadIdx.x; i < 384; i += 256) {
        int hd = i / 48, k = i % 48;
        int bh = bblk * HEADS + hd;
        sm[i] = Sp[(bh * 2 + 0) * 48 + k] + Sp[(bh * 2 + 1) * 48 + k];
    }
    __syncthreads();
    if (threadIdx.x < 48) {
        int hd = threadIdx.x / 6, c = threadIdx.x % 6;
        const float* base = sm + hd * 48;
        float rqv = 1.f / fmaxf(sqrtf(base[36 + c]), 1e-12f);
        float tmp = wts[W_TEMP + hd];
        float row[CPH];
        #pragma unroll
        for (int d = 0; d < CPH; d++) {
            float rkv = 1.f / fmaxf(sqrtf(base[42 + d]), 1e-12f);
            row[d] = base[c * CPH + d] * rqv * rkv * tmp;
        }
        float mx = row[0];
        #pragma unroll
        for (int d = 1; d < CPH; d++) mx = fmaxf(mx, row[d]);
        float sum = 0.f;
        #pragma unroll
        for (int d = 0; d < CPH; d++) { row[d] = expf(row[d] - mx); sum += row[d]; }
        float inv = 1.f / sum;
        #pragma unroll
        for (int d = 0; d < CPH; d++) S_l[hd * 36 + c * CPH + d] = row[d] * inv;
    }
    if (threadIdx.x >= 64 && threadIdx.x < 160) {
        int i = threadIdx.x - 64;
        int which = i / 48, co = i % 48;
        const float* g = gap + bblk * Cc;
        float sacc = wts[(which ? W_CA2B : W_CA1B) + co];
        #pragma unroll
        for (int c = 0; c < Cc; c++)
            sacc += wts[(which ? W_CA2W : W_CA1W) + co * Cc + c] * g[c];
        caL[i] = sacc;
    }
    __syncthreads();

    // kproj: Dk = Wkp @ h_bf[p]
    short8 H0 = *(const short8*)(h_bf + (size_t)p * 96 + q * 8);
    short8 H1 = *(const short8*)(h_bf + (size_t)p * 96 + 32 + q * 8);
    short8 H2 = *(const short8*)(h_bf + (size_t)p * 96 + 64 + q * 8);
    f32x4 Dk[3];
    #pragma unroll
    for (int t = 0; t < 3; t++) {
        short8 A0 = *(const short8*)(Wkp + (16 * t + m) * 96 + q * 8);
        short8 A1 = *(const short8*)(Wkp + (16 * t + m) * 96 + 32 + q * 8);
        short8 A2 = *(const short8*)(Wkp + (16 * t + m) * 96 + 64 + q * 8);
        f32x4 z = {0.f, 0.f, 0.f, 0.f};
        f32x4 D = __builtin_amdgcn_mfma_f32_16x16x32_bf16(A0, H0, z, 0, 0, 0);
        D = __builtin_amdgcn_mfma_f32_16x16x32_bf16(A1, H1, D, 0, 0, 0);
        Dk[t] = __builtin_amdgcn_mfma_f32_16x16x32_bf16(A2, H2, D, 0, 0, 0);
    }

    // mdta B-fragments via S@v for this pixel (v from LDS)
    short8 Bm0, Bm1;
    #pragma unroll
    for (int jj = 0; jj < 8; jj++) {
        int c0 = q * 8 + jj;
        int hd0 = c0 / 6, cc0 = c0 - 6 * hd0;
        float a = 0.f;
        #pragma unroll
        for (int d = 0; d < CPH; d++)
            a += S_l[hd0 * 36 + cc0 * 6 + d] * b2f(vS[(hd0 * 6 + d) * 68 + wl]);
        Bm0[jj] = (short)f2b(a);
        int c1 = 32 + q * 8 + jj;
        float bv = 0.f;
        if (c1 < 48) {
            int hd1 = c1 / 6, cc1 = c1 - 6 * hd1;
            #pragma unroll
            for (int d = 0; d < CPH; d++)
                bv += S_l[hd1 * 36 + cc1 * 6 + d] * b2f(vS[(hd1 * 6 + d) * 68 + wl]);
        }
        Bm1[jj] = (short)f2b(bv);
    }

    // mproj + epilogue
    #pragma unroll
    for (int t = 0; t < 3; t++) {
        short8 A0 = *(const short8*)(Wmp + (16 * t + m) * 64 + q * 8);
        short8 A1 = *(const short8*)(Wmp + (16 * t + m) * 64 + 32 + q * 8);
        f32x4 z = {0.f, 0.f, 0.f, 0.f};
        f32x4 D = __builtin_amdgcn_mfma_f32_16x16x32_bf16(A0, Bm0, z, 0, 0, 0);
        D = __builtin_amdgcn_mfma_f32_16x16x32_bf16(A1, Bm1, D, 0, 0, 0);
        #pragma unroll
        for (int g = 0; g < 4; g++) {
            int co = 16 * t + 4 * q + g;
            int idx = (bblk * Cc + co) * HW + hw;
            float xv = fl ? b2f(((const ushortT*)x)[idx]) : ((const float*)x)[idx];
            float res = xv + Dk[t][g] * caL[co] + D[g] * caL[48 + co];
            if (fl) ((ushortT*)out)[idx] = f2b(res);
            else    ((float*)out)[idx] = res;
        }
    }
}

// ---------------- host launch ----------------
extern "C" void kernel_launch(void* const* d_in, const int* in_sizes, int n_in,
                              void* d_out, int out_size, void* d_ws, size_t ws_size,
                              hipStream_t stream) {
    float* ws_f = (float*)d_ws;

    ushortT* bufA  = (ushortT*)(ws_f + FA);     // t1 bf16
    ushortT* bufB  = (ushortT*)(ws_f + FB);     // t2 bf16
    ushortT* x1g   = (ushortT*)(ws_f + FC);
    ushortT* uf    = (ushortT*)(ws_f + FD);
    ushortT* araw  = (ushortT*)(ws_f + FARAW);
    ushortT* attn_t= (ushortT*)(ws_f + FATT);
    float* gap   = ws_f + FGAP;
    float* Sp    = ws_f + FSP;
    float* wts   = ws_f + FW;
    ushortT* att_bf  = (ushortT*)(ws_f + FATTB);
    ushortT* Wt      = (ushortT*)(ws_f + FWT);
    float2* stats    = (float2*)(ws_f + FSTAT);
    ushortT* h_bf    = (ushortT*)(ws_f + FHBF);
    ushortT* Wpw     = (ushortT*)(ws_f + FWPW);
    ushortT* Wqk     = (ushortT*)(ws_f + FWQK);
    ushortT* Wkp     = (ushortT*)(ws_f + FWKP);
    ushortT* Wmp     = (ushortT*)(ws_f + FWMP);
    ushortT* qkvr    = (ushortT*)(ws_f + FQKVR);
    ushortT* qkv     = (ushortT*)(ws_f + FQKV);

    const uint32_t* n1w_raw = (const uint32_t*)d_in[1];

    static const int wsizes[27] = {48,48,48,48,4608,864,4608,864,4608,432,24,384,32,
                                   1536,32,110592,3072,32,96,8,6912,1296,2304,2304,48,2304,48};
    static const int woffs[27] = {W_N1W,W_N1B,W_N2W,W_N2B,W_KDW1,W_KDW2,W_KC1A,W_KC1B,
                                  W_KPROJ,W_C2AW,W_C2AB,W_C2BW,W_C2BB,W_C211W,W_C211B,
                                  W_KW,W_KB,W_ATTG,W_GA1,W_TEMP,W_QKVW,W_QKVDW,W_MPROJ,
                                  W_CA1W,W_CA1B,W_CA2W,W_CA2B};
    ConvPack cp;
    for (int i = 0; i < 27; i++) {
        cp.src[i] = d_in[i + 1];
        cp.dstoff[i] = woffs[i];
        cp.n[i] = wsizes[i];
    }
    RawW rw;
    rw.kdw1 = d_in[5]; rw.kc1a = d_in[7]; rw.c211w = d_in[14]; rw.qkvw = d_in[21];
    rw.kproj = d_in[9]; rw.mproj = d_in[23]; rw.kw = d_in[16]; rw.kb = d_in[17];
    rw.n1w = d_in[1]; rw.n1b = d_in[2]; rw.n2w = d_in[3]; rw.n2b = d_in[4];

    k_prep<<<dim3(64, 37), 256, 0, stream>>>(cp, rw, wts, Wt, Wpw, Wqk, Wkp, Wmp,
                                             d_in[0], gap, stats, n1w_raw);
    k_pw1m<<<dim3(640, 2), 256, 0, stream>>>(d_in[0], stats, Wpw, Wqk, rw, wts,
                                             bufA, bufB, attn_t, qkvr, araw, n1w_raw);
    k_dw<<<dim3(8, 344), 256, 0, stream>>>(bufA, bufB, qkvr, araw, attn_t, wts,
                                           x1g, uf, qkv, att_bf);
    k_kba<<<dim3(64, 25), 256, 0, stream>>>(att_bf, uf, x1g, Wt, qkv, wts, h_bf, Sp);
    k_finalm<<<dim3(256), 256, 0, stream>>>(d_in[0], n1w_raw, h_bf, Wkp, Wmp,
                                            qkv, Sp, gap, wts, d_out);
}

// Round 10
// 185.584 us; speedup vs baseline: 1.0107x; 1.0107x over previous
//
#include <hip/hip_runtime.h>
#include <hip/hip_bf16.h>
#include <cstdint>

typedef unsigned short ushortT;
typedef __attribute__((ext_vector_type(8))) short short8;
typedef __attribute__((ext_vector_type(8))) unsigned short ushort8v;
typedef __attribute__((ext_vector_type(4))) float f32x4;
typedef __attribute__((ext_vector_type(4))) unsigned short ushort4v;

// ---------------- problem constants ----------------
static constexpr int Bn = 4, Cc = 48, Hh = 64, Wd = 64, HW = 4096;
static constexpr int HID = 96, NSET = 32, INTERC = 24, HEADS = 8, CPH = 6;

// ---------------- ws layout (float offsets) ----------------
static constexpr int FA    = 786432;    // t1 bf16 planar
static constexpr int FB    = 2359296;   // t2 bf16 planar
static constexpr int FC    = 3932160;   // x1g bf16 planar
static constexpr int FD    = 5505024;   // uf bf16 planar
static constexpr int FARAW = 7077888;   // araw bf16 planar
static constexpr int FATT  = 7471104;   // attn_t bf16 [p][32]
static constexpr int FGAP  = 8781824;   // 192 fp32
static constexpr int FSP   = 8782400;   // Sp partials fp32 (32bh x 2chunk x 48)
static constexpr int FW    = 8790000;   // 147200 fp32 weights
static constexpr int FATTB = 8937200;   // att_bf [p][32] bf16
static constexpr int FWT   = 9199344;   // Wt bf16 (KBA)
static constexpr int FSTAT = 9260784;   // LN stats float2[16384] (mu, rstd)
static constexpr int FHBF  = 10309360;  // h_bf [p][96] bf16
static constexpr int FWPW  = 11095792;  // Wpw [224][64] bf16
static constexpr int FWQK  = 11102960;  // Wqk [144][64] bf16
static constexpr int FWKP  = 11107568;  // Wkp [48][96] bf16
static constexpr int FWMP  = 11109872;  // Wmp [48][64] bf16
static constexpr int FQKVR = 11111424;  // qkvr bf16 planar
static constexpr int FQKV  = 13470720;  // qkv bf16 planar

// ---- weight offsets inside FW ----
static constexpr int W_N1W=0, W_N1B=48, W_N2W=96, W_N2B=144;
static constexpr int W_KDW1=192, W_KDW2=4800, W_KC1A=5664, W_KC1B=10272;
static constexpr int W_KPROJ=11136, W_C2AW=15744, W_C2AB=16176;
static constexpr int W_C2BW=16200, W_C2BB=16584, W_C211W=16616, W_C211B=18152;
static constexpr int W_KW=18184, W_KB=128776, W_ATTG=131848, W_GA1=131880;
static constexpr int W_TEMP=131976, W_QKVW=131984, W_QKVDW=138896, W_MPROJ=140192;
static constexpr int W_CA1W=142496, W_CA1B=144800, W_CA2W=144848, W_CA2B=147152;

__device__ __forceinline__ float b2f(ushortT u) {
    union { uint32_t i; float f; } v; v.i = ((uint32_t)u) << 16; return v.f;
}
__device__ __forceinline__ ushortT f2b(float f) {
    union { float f; uint32_t i; } v; v.f = f;
    uint32_t i = v.i;
    uint32_t lsb = (i >> 16) & 1u;
    i += 0x7fffu + lsb;
    return (ushortT)(i >> 16);
}
__device__ __forceinline__ int dtype_bf16(const uint32_t* n1w_raw) {
    return n1w_raw[0] == 0x3F803F80u;
}
__device__ __forceinline__ ushortT raw_bf(const void* p, int idx, int fl) {
    return fl ? ((const ushortT*)p)[idx] : f2b(((const float*)p)[idx]);
}
__device__ __forceinline__ float raw_f(const void* p, int idx, int fl) {
    return fl ? b2f(((const ushortT*)p)[idx]) : ((const float*)p)[idx];
}

// ---------------- prep: convert weights + gap + LN stats. grid (64, 8) ----------------
struct ConvPack {
    const void* src[27];
    int dstoff[27];
    int pre[28];      // prefix sums of sizes; pre[27] = total
};
struct RawW {
    const void* kdw1; const void* kc1a; const void* c211w; const void* qkvw;
    const void* kproj; const void* mproj; const void* kw; const void* kb;
    const void* n1w; const void* n1b; const void* n2w; const void* n2b;
};

__global__ void __launch_bounds__(256) k_prep(ConvPack p, RawW rw, float* __restrict__ dst,
                       ushortT* __restrict__ Wt, ushortT* __restrict__ Wpw,
                       ushortT* __restrict__ Wqk, ushortT* __restrict__ Wkp,
                       ushortT* __restrict__ Wmp,
                       const void* __restrict__ x, float* __restrict__ gap,
                       float2* __restrict__ stats,
                       const uint32_t* __restrict__ n1w_raw) {
    int fl = dtype_bf16(n1w_raw);
    int y = blockIdx.y;
    int tid = threadIdx.x;
    if (y == 0) {
        // all 27 small fp32 weight copies, flattened
        int total = p.pre[27];
        for (int g = blockIdx.x * 256 + tid; g < total; g += 64 * 256) {
            int lo = 0, hi = 26;
            while (lo < hi) { int mid = (lo + hi + 1) >> 1; if (g >= p.pre[mid]) lo = mid; else hi = mid - 1; }
            int off = g - p.pre[lo];
            dst[p.dstoff[lo] + off] = raw_f(p.src[lo], off, fl);
        }
    } else if (y == 1) {
        for (int u = blockIdx.x * 256 + tid; u < 24 * 160 * 32; u += 64 * 256) {
            int n = u & 31;
            int rest = u >> 5;
            int r = rest % 160;
            int gr = rest / 160;
            ushortT out;
            if (r < 144) {
                int j = r >> 2, i = r & 3;
                out = raw_bf(rw.kw, n * 3456 + gr * 144 + i * 36 + j, fl);
            } else if (r < 148) {
                out = raw_bf(rw.kb, n * HID + gr * 4 + (r - 144), fl);
            } else out = 0;
            Wt[u] = out;
        }
    } else if (y == 2) {
        // packed bf16 weight matrices: Wpw 14336 | Wqk 9216 | Wkp 4608 | Wmp 3072
        for (int u = blockIdx.x * 256 + tid; u < 31232; u += 64 * 256) {
            if (u < 14336) {
                int co = u >> 6, c = u & 63;
                ushortT v = 0;
                if (c < 48) {
                    if (co < 96)       v = raw_bf(rw.kdw1,  co * 48 + c, fl);
                    else if (co < 192) v = raw_bf(rw.kc1a,  (co - 96) * 48 + c, fl);
                    else               v = raw_bf(rw.c211w, (co - 192) * 48 + c, fl);
                }
                Wpw[u] = v;
            } else if (u < 23552) {
                int v2 = u - 14336;
                int co = v2 >> 6, c = v2 & 63;
                Wqk[v2] = (c < 48) ? raw_bf(rw.qkvw, co * 48 + c, fl) : (ushortT)0;
            } else if (u < 28160) {
                int v2 = u - 23552;
                int co = v2 / 96, c = v2 % 96;
                Wkp[v2] = raw_bf(rw.kproj, co * 96 + c, fl);
            } else {
                int v2 = u - 28160;
                int co = v2 >> 6, c = v2 & 63;
                Wmp[v2] = (c < 48) ? raw_bf(rw.mproj, co * 48 + c, fl) : (ushortT)0;
            }
        }
    } else if (y == 3) {
        // gap: 3 bc per block, vectorized loads (16 elems/thread)
        __shared__ float red[4];
        for (int k = 0; k < 3; k++) {
            int bc = blockIdx.x * 3 + k;
            float s = 0.f;
            if (fl) {
                const ushortT* xb = (const ushortT*)x + (size_t)bc * HW + tid * 16;
                ushort8v a = *(const ushort8v*)xb;
                ushort8v b = *(const ushort8v*)(xb + 8);
                #pragma unroll
                for (int i = 0; i < 8; i++) s += b2f(a[i]) + b2f(b[i]);
            } else {
                const float* xb = (const float*)x + (size_t)bc * HW + tid * 16;
                #pragma unroll
                for (int q4 = 0; q4 < 4; q4++) {
                    float4 v = *(const float4*)(xb + q4 * 4);
                    s += v.x + v.y + v.z + v.w;
                }
            }
            #pragma unroll
            for (int o = 32; o > 0; o >>= 1) s += __shfl_down(s, o);
            int lane = tid & 63, wv = tid >> 6;
            if (lane == 0) red[wv] = s;
            __syncthreads();
            if (tid == 0)
                gap[bc] = (red[0] + red[1] + red[2] + red[3]) * (1.f / HW);
            __syncthreads();
        }
    } else {
        // y = 4..7: LN stats only: 4 lanes per pixel, 12 ch each -> (mu, rstd)
        int slice = y - 4;
        int pp = slice * 4096 + blockIdx.x * 64 + (tid >> 2);
        int part = tid & 3;
        int b = pp >> 12, hw = pp & 4095;
        const ushortT* xbh = (const ushortT*)x + (size_t)b * Cc * HW + hw;
        const float*  xbf = (const float*)x + (size_t)b * Cc * HW + hw;
        float s = 0.f, ss = 0.f;
        #pragma unroll
        for (int j = 0; j < 12; j++) {
            int c = part * 12 + j;
            float t = fl ? b2f(xbh[c * HW]) : xbf[c * HW];
            s += t; ss += t * t;
        }
        s  += __shfl_xor(s, 1);  s  += __shfl_xor(s, 2);
        ss += __shfl_xor(ss, 1); ss += __shfl_xor(ss, 2);
        float mu = s * (1.f / Cc);
        float var = ss * (1.f / Cc) - mu * mu;
        float r = rsqrtf(var + 1e-6f);
        if (part == 0) {
            float2 o; o.x = mu; o.y = r;
            stats[pp] = o;
        }
    }
}

// 6-tap raw row loader (cols w0-1..w0+4, zero outside [0,64))
__device__ __forceinline__ void load6(const void* plane, int fl, int base, int w0, float* f) {
    if (fl) {
        const ushortT* rp = (const ushortT*)plane + base;
        ushort4v mm = *(const ushort4v*)rp;
        f[1] = b2f(mm[0]); f[2] = b2f(mm[1]); f[3] = b2f(mm[2]); f[4] = b2f(mm[3]);
        f[0] = (w0 > 0)  ? b2f(rp[-1]) : 0.f;
        f[5] = (w0 < 60) ? b2f(rp[4])  : 0.f;
    } else {
        const float* rp = (const float*)plane + base;
        float4 mm = *(const float4*)rp;
        f[1] = mm.x; f[2] = mm.y; f[3] = mm.z; f[4] = mm.w;
        f[0] = (w0 > 0)  ? rp[-1] : 0.f;
        f[5] = (w0 < 60) ? rp[4]  : 0.f;
    }
}

// 8-px depthwise 3x3 row accumulate
__device__ __forceinline__ void dwconv8(const ushortT* plane, const float* wk,
                                        int h, int w0, float* aa) {
    #pragma unroll
    for (int ki = 0; ki < 3; ki++) {
        int hh = h + ki - 1;
        if ((unsigned)hh < 64u) {
            const ushortT* row = plane + hh * 64 + w0;
            ushort4v v0 = *(const ushort4v*)row;
            ushort4v v1 = *(const ushort4v*)(row + 4);
            float f[10];
            f[0] = (w0 > 0)  ? b2f(row[-1]) : 0.f;
            f[1] = b2f(v0[0]); f[2] = b2f(v0[1]); f[3] = b2f(v0[2]); f[4] = b2f(v0[3]);
            f[5] = b2f(v1[0]); f[6] = b2f(v1[1]); f[7] = b2f(v1[2]); f[8] = b2f(v1[3]);
            f[9] = (w0 < 56) ? b2f(row[8])  : 0.f;
            float k0 = wk[ki * 3], k1 = wk[ki * 3 + 1], k2 = wk[ki * 3 + 2];
            #pragma unroll
            for (int i = 0; i < 8; i++)
                aa[i] += k0 * f[i] + k1 * f[i + 1] + k2 * f[i + 2];
        }
    }
}

// ---------------- pw1m: 1D grid(896). id<256: [224x48]->t1,t2,attn_t ; 256<=id<512: [144x48]->qkvr ; id>=512: c2a->araw ----------------
__global__ void __launch_bounds__(256) k_pw1m(const void* __restrict__ x, const float2* __restrict__ stats,
                       const ushortT* __restrict__ Wpw, const ushortT* __restrict__ Wqk,
                       RawW rw, const float* __restrict__ wts,
                       ushortT* __restrict__ t1, ushortT* __restrict__ t2,
                       ushortT* __restrict__ attn_t, ushortT* __restrict__ qkvr,
                       ushortT* __restrict__ araw,
                       const uint32_t* __restrict__ n1w_raw) {
    int fl = dtype_bf16(n1w_raw);
    int id = blockIdx.x;
    if (id >= 512) {
        // c2a grouped 3x3 conv with inline LN (n1) from stats
        int sub = id - 512;                // 0..383
        int o = sub >> 4;                  // 0..23
        int xb = sub & 15;
        int pbase = xb * 1024 + threadIdx.x * 4;
        int b = pbase >> 12, hw = pbase & 4095, h = hw >> 6, w0 = hw & 63;
        const float2* st = stats + b * 4096;
        float nw0 = raw_f(rw.n1w, 2 * o, fl),     nb0 = raw_f(rw.n1b, 2 * o, fl);
        float nw1 = raw_f(rw.n1w, 2 * o + 1, fl), nb1 = raw_f(rw.n1b, 2 * o + 1, fl);
        const void* pl0;
        const void* pl1;
        if (fl) {
            pl0 = (const void*)((const ushortT*)x + (size_t)(b * Cc + 2 * o) * HW);
            pl1 = (const void*)((const ushortT*)x + (size_t)(b * Cc + 2 * o + 1) * HW);
        } else {
            pl0 = (const void*)((const float*)x + (size_t)(b * Cc + 2 * o) * HW);
            pl1 = (const void*)((const float*)x + (size_t)(b * Cc + 2 * o + 1) * HW);
        }
        const float* wk = wts + W_C2AW + (o * 2) * 9;
        float bias = wts[W_C2AB + o];
        float a0 = bias, a1 = bias, a2 = bias, a3 = bias;
        #pragma unroll
        for (int ki = 0; ki < 3; ki++) {
            int hh = h + ki - 1;
            if ((unsigned)hh < 64u) {
                int base = hh * 64 + w0;
                float mu[6], rr[6];
                #pragma unroll
                for (int i = 0; i < 6; i++) {
                    int c = w0 + i - 1;
                    if ((unsigned)c < 64u) {
                        float2 s2 = st[hh * 64 + c];
                        mu[i] = s2.x; rr[i] = s2.y;
                    } else { mu[i] = 0.f; rr[i] = 0.f; }
                }
                float f[6], g[6];
                float k0a = wk[ki * 3], k1a = wk[ki * 3 + 1], k2a = wk[ki * 3 + 2];
                float k0b = wk[9 + ki * 3], k1b = wk[9 + ki * 3 + 1], k2b = wk[9 + ki * 3 + 2];
                load6(pl0, fl, base, w0, f);
                g[0] = (w0 > 0)  ? nw0 * ((f[0] - mu[0]) * rr[0]) + nb0 : 0.f;
                #pragma unroll
                for (int i = 1; i < 5; i++) g[i] = nw0 * ((f[i] - mu[i]) * rr[i]) + nb0;
                g[5] = (w0 < 60) ? nw0 * ((f[5] - mu[5]) * rr[5]) + nb0 : 0.f;
                a0 += k0a * g[0] + k1a * g[1] + k2a * g[2];
                a1 += k0a * g[1] + k1a * g[2] + k2a * g[3];
                a2 += k0a * g[2] + k1a * g[3] + k2a * g[4];
                a3 += k0a * g[3] + k1a * g[4] + k2a * g[5];
                load6(pl1, fl, base, w0, f);
                g[0] = (w0 > 0)  ? nw1 * ((f[0] - mu[0]) * rr[0]) + nb1 : 0.f;
                #pragma unroll
                for (int i = 1; i < 5; i++) g[i] = nw1 * ((f[i] - mu[i]) * rr[i]) + nb1;
                g[5] = (w0 < 60) ? nw1 * ((f[5] - mu[5]) * rr[5]) + nb1 : 0.f;
                a0 += k0b * g[0] + k1b * g[1] + k2b * g[2];
                a1 += k0b * g[1] + k1b * g[2] + k2b * g[3];
                a2 += k0b * g[2] + k1b * g[3] + k2b * g[4];
                a3 += k0b * g[3] + k1b * g[4] + k2b * g[5];
            }
        }
        ushort4v out;
        out[0] = f2b(a0); out[1] = f2b(a1); out[2] = f2b(a2); out[3] = f2b(a3);
        *(ushort4v*)(araw + (size_t)(b * INTERC + o) * HW + hw) = out;
        return;
    }

    // MFMA blocks: stage normalized bf16 fragments into LDS
    __shared__ ushortT xS[64][72];     // [pixel][ch], pad 72
    int side = id >> 8;                // 0: Wpw-side, 1: Wqk-side
    int blk = id & 255;
    int p0 = blk * 64;
    int b = p0 >> 12, hw0 = p0 & 4095;
    const float2* st = stats + b * 4096 + hw0;
    const void* nwp = side ? rw.n2w : rw.n1w;
    const void* nbp = side ? rw.n2b : rw.n1b;
    const ushortT* xh = (const ushortT*)x + (size_t)b * Cc * HW + hw0;
    const float*  xf = (const float*)x  + (size_t)b * Cc * HW + hw0;
    for (int i = threadIdx.x; i < 48 * 64; i += 256) {
        int ch = i >> 6, w = i & 63;
        float v = fl ? b2f(xh[(size_t)ch * HW + w]) : xf[(size_t)ch * HW + w];
        float2 s2 = st[w];
        float yv = (v - s2.x) * s2.y;
        xS[w][ch] = f2b(raw_f(nwp, ch, fl) * yv + raw_f(nbp, ch, fl));
    }
    for (int i = threadIdx.x; i < 16 * 64; i += 256) {
        int ch = 48 + (i >> 6), w = i & 63;
        xS[w][ch] = 0;
    }
    __syncthreads();

    int wave = threadIdx.x >> 6, lane = threadIdx.x & 63;
    int m = lane & 15, q = lane >> 4;
    int pl = wave * 16 + m;
    int p = p0 + pl;
    int hw = p & 4095;
    short8 B0 = *(const short8*)&xS[pl][q * 8];
    short8 B1 = *(const short8*)&xS[pl][32 + q * 8];
    if (side == 0) {
        #pragma unroll
        for (int t = 0; t < 14; t++) {
            short8 A0 = *(const short8*)(Wpw + (16 * t + m) * 64 + q * 8);
            short8 A1 = *(const short8*)(Wpw + (16 * t + m) * 64 + 32 + q * 8);
            f32x4 z = {0.f, 0.f, 0.f, 0.f};
            f32x4 D = __builtin_amdgcn_mfma_f32_16x16x32_bf16(A0, B0, z, 0, 0, 0);
            D = __builtin_amdgcn_mfma_f32_16x16x32_bf16(A1, B1, D, 0, 0, 0);
            #pragma unroll
            for (int g = 0; g < 4; g++) {
                int co = 16 * t + 4 * q + g;
                if (t < 6) t1[(size_t)(b * HID + co) * HW + hw] = f2b(D[g]);
                else if (t < 12) t2[(size_t)(b * HID + (co - 96)) * HW + hw] = f2b(D[g]);
                else {
                    int n = co - 192;
                    attn_t[(size_t)p * 32 + n] = f2b(D[g] + wts[W_C211B + n]);
                }
            }
        }
    } else {
        #pragma unroll
        for (int t = 0; t < 9; t++) {
            short8 A0 = *(const short8*)(Wqk + (16 * t + m) * 64 + q * 8);
            short8 A1 = *(const short8*)(Wqk + (16 * t + m) * 64 + 32 + q * 8);
            f32x4 z = {0.f, 0.f, 0.f, 0.f};
            f32x4 D = __builtin_amdgcn_mfma_f32_16x16x32_bf16(A0, B0, z, 0, 0, 0);
            D = __builtin_amdgcn_mfma_f32_16x16x32_bf16(A1, B1, D, 0, 0, 0);
            #pragma unroll
            for (int g = 0; g < 4; g++) {
                int co = 16 * t + 4 * q + g;
                qkvr[(size_t)(b * 144 + co) * HW + hw] = f2b(D[g]);
            }
        }
    }
}

// ---------------- dw: y<96 kdw2->gelu->x1g ; y<192 kc1b->uf ; y<336 qkvdw->qkv ; y<344 att-assembly->att_bf. grid (8, 344), 8 px/thread ----------------
__global__ void __launch_bounds__(256) k_dw(const ushortT* __restrict__ t1, const ushortT* __restrict__ t2,
                     const ushortT* __restrict__ qkvr, const ushortT* __restrict__ araw,
                     const ushortT* __restrict__ attn_t, const float* __restrict__ wts,
                     ushortT* __restrict__ x1g, ushortT* __restrict__ uf,
                     ushortT* __restrict__ qkv, ushortT* __restrict__ att_bf) {
    int y = blockIdx.y;

    if (y < 336) {
        int pbase = blockIdx.x * 2048 + threadIdx.x * 8;
        int b = pbase >> 12, hw = pbase & 4095, h = hw >> 6, w0 = hw & 63;
        const ushortT* plane;
        const float* wk;
        ushortT* dst;
        size_t idx;
        if (y < 96) {
            plane = t1 + (size_t)(b * HID + y) * HW;
            wk = wts + W_KDW2 + y * 9;
            dst = x1g; idx = (size_t)(b * HID + y) * HW + hw;
        } else if (y < 192) {
            int c = y - 96;
            plane = t2 + (size_t)(b * HID + c) * HW;
            wk = wts + W_KC1B + c * 9;
            dst = uf; idx = (size_t)(b * HID + c) * HW + hw;
        } else {
            int ch = y - 192;
            plane = qkvr + (size_t)(b * 144 + ch) * HW;
            wk = wts + W_QKVDW + ch * 9;
            dst = qkv; idx = (size_t)(b * 144 + ch) * HW + hw;
        }

        float aa[8];
        #pragma unroll
        for (int i = 0; i < 8; i++) aa[i] = 0.f;
        dwconv8(plane, wk, h, w0, aa);

        uint32_t pk[4];
        if (y < 96) {
            #pragma unroll
            for (int i = 0; i < 4; i++) {
                float g0 = 0.5f * aa[2*i]   * (1.f + erff(aa[2*i]   * 0.70710678118654752f));
                float g1 = 0.5f * aa[2*i+1] * (1.f + erff(aa[2*i+1] * 0.70710678118654752f));
                pk[i] = (uint32_t)f2b(g0) | ((uint32_t)f2b(g1) << 16);
            }
        } else {
            #pragma unroll
            for (int i = 0; i < 4; i++)
                pk[i] = (uint32_t)f2b(aa[2*i]) | ((uint32_t)f2b(aa[2*i+1]) << 16);
        }
        uint4 o; o.x = pk[0]; o.y = pk[1]; o.z = pk[2]; o.w = pk[3];
        *(uint4*)(dst + idx) = o;
    } else {
        // att-assembly: att = attgamma*c2b(SG(araw)) + attn_t -> att_bf (light, per-pixel)
        int p = ((y - 336) * 8 + blockIdx.x) * 256 + threadIdx.x;
        int b = p >> 12, hw = p & 4095;
        const ushortT* ab = araw + (size_t)b * INTERC * HW + hw;
        float sg[12];
        #pragma unroll
        for (int i = 0; i < 12; i++) sg[i] = b2f(ab[i * HW]) * b2f(ab[(12 + i) * HW]);
        const ushortT* ct = attn_t + (size_t)p * 32;
        uint32_t packed[16];
        #pragma unroll
        for (int nq = 0; nq < 16; nq++) {
            float v2[2];
            #pragma unroll
            for (int u = 0; u < 2; u++) {
                int n = nq * 2 + u;
                float a = wts[W_C2BB + n];
                #pragma unroll
                for (int c = 0; c < 12; c++) a += wts[W_C2BW + n * 12 + c] * sg[c];
                v2[u] = wts[W_ATTG + n] * a + b2f(ct[n]);
            }
            packed[nq] = (uint32_t)f2b(v2[0]) | ((uint32_t)f2b(v2[1]) << 16);
        }
        uint4* dst = (uint4*)(att_bf + (size_t)p * 32);
        #pragma unroll
        for (int qd = 0; qd < 4; qd++) {
            uint4 v; v.x = packed[qd*4]; v.y = packed[qd*4+1]; v.z = packed[qd*4+2]; v.w = packed[qd*4+3];
            dst[qd] = v;
        }
    }
}

// ---------------- kba (+smat): y<24 KBA core (LDS-staged taps) -> h_bf ; y==24 smat partials -> Sp. grid (64,25) x 256 ----------------
__global__ void __launch_bounds__(256) k_kba(const ushortT* __restrict__ att_bf, const ushortT* __restrict__ uf,
                     const ushortT* __restrict__ x1g, const ushortT* __restrict__ Wt,
                     const ushortT* __restrict__ qkv, const float* __restrict__ wts,
                     ushortT* __restrict__ h_bf, float* __restrict__ Sp) {
    __shared__ float red[48 * 4];
    __shared__ ushortT ufS[4][6][72];   // [ci][row h0-1..h0+4][col -1..64], pad 72
    if (blockIdx.y == 24) {
        int sub = blockIdx.x;               // 0..63
        int bh = sub >> 1, chunk = sub & 1;
        int b = bh / HEADS, hd = bh % HEADS;
        const ushortT* qb = qkv + (size_t)(b * 144 + hd * CPH) * HW;
        const ushortT* kb = qkv + (size_t)(b * 144 + 48 + hd * CPH) * HW;
        float acc[48];
        #pragma unroll
        for (int t = 0; t < 48; t++) acc[t] = 0.f;
        #pragma unroll
        for (int i = 0; i < 8; i++) {
            int px = chunk * 2048 + i * 256 + threadIdx.x;
            float qv[CPH], kv[CPH];
            #pragma unroll
            for (int c = 0; c < CPH; c++) { qv[c] = b2f(qb[c * HW + px]); kv[c] = b2f(kb[c * HW + px]); }
            #pragma unroll
            for (int c = 0; c < CPH; c++) {
                #pragma unroll
                for (int d = 0; d < CPH; d++) acc[c * CPH + d] += qv[c] * kv[d];
                acc[36 + c] += qv[c] * qv[c];
                acc[42 + c] += kv[c] * kv[c];
            }
        }
        int lane = threadIdx.x & 63, wv = threadIdx.x >> 6;
        #pragma unroll
        for (int t = 0; t < 48; t++) {
            float v = acc[t];
            #pragma unroll
            for (int o = 32; o > 0; o >>= 1) v += __shfl_down(v, o);
            if (lane == 0) red[t * 4 + wv] = v;
        }
        __syncthreads();
        if (threadIdx.x < 48)
            Sp[(bh * 2 + chunk) * 48 + threadIdx.x] =
                red[threadIdx.x * 4] + red[threadIdx.x * 4 + 1] +
                red[threadIdx.x * 4 + 2] + red[threadIdx.x * 4 + 3];
        return;
    }

    int wave = threadIdx.x >> 6, lane = threadIdx.x & 63;
    int m = lane & 15, q = lane >> 4;
    int gr = blockIdx.y;
    int b = blockIdx.x >> 4;            // block covers 256 consecutive pixels
    int h0 = (blockIdx.x & 15) * 4;     // rows h0..h0+3, wave handles row h0+wave

    // stage uf tile: 4 ch x 6 rows (h0-1..h0+4) x 66 cols (-1..64), halo = 0
    #pragma unroll
    for (int pr = 0; pr < 24; pr += 4) {
        int pp = pr + wave;
        int ci = pp / 6, r = pp % 6;
        int hh = h0 - 1 + r;
        ushortT v = 0;
        if ((unsigned)hh < 64u)
            v = uf[(size_t)(b * HID + gr * 4 + ci) * HW + hh * 64 + lane];
        ufS[ci][r][lane + 1] = v;
        if (lane < 2) ufS[ci][r][lane * 65] = 0;   // cols -1 and 64
    }

    short8 A[10];
    const ushortT* wtg = Wt + gr * 160 * 32;
    #pragma unroll
    for (int t = 0; t < 10; t++)
        A[t] = *(const short8*)(wtg + (16 * t + m) * 32 + q * 8);

    __syncthreads();

    for (int tile = 0; tile < 4; tile++) {
        int p = blockIdx.x * 256 + wave * 64 + tile * 16 + m;
        int hw = p & 4095, w = hw & 63;

        short8 Bf = *(const short8*)(att_bf + (size_t)p * 32 + q * 8);

        f32x4 D[10];
        #pragma unroll
        for (int t = 0; t < 10; t++) {
            f32x4 z = {0.f, 0.f, 0.f, 0.f};
            D[t] = __builtin_amdgcn_mfma_f32_16x16x32_bf16(A[t], Bf, z, 0, 0, 0);
        }

        float s0 = 0.f, s1 = 0.f, s2 = 0.f, s3 = 0.f;
        #pragma unroll
        for (int t = 0; t < 9; t++) {
            int j = 4 * t + q;
            int ci = j / 9;
            int kk = j - 9 * ci;
            int ki = kk / 3, kj = kk - 3 * ki;
            float tap = b2f(ufS[ci][wave + ki][w + kj]);
            s0 += D[t][0] * tap;
            s1 += D[t][1] * tap;
            s2 += D[t][2] * tap;
            s3 += D[t][3] * tap;
        }
        s0 += D[9][0]; s1 += D[9][1]; s2 += D[9][2]; s3 += D[9][3];

        s0 += __shfl_xor(s0, 16); s0 += __shfl_xor(s0, 32);
        s1 += __shfl_xor(s1, 16); s1 += __shfl_xor(s1, 32);
        s2 += __shfl_xor(s2, 16); s2 += __shfl_xor(s2, 32);
        s3 += __shfl_xor(s3, 16); s3 += __shfl_xor(s3, 32);

        float sel = (q == 0) ? s0 : ((q == 1) ? s1 : ((q == 2) ? s2 : s3));
        int ch = gr * 4 + q;
        size_t idx = (size_t)(b * HID + ch) * HW + hw;
        float x2 = sel * wts[W_GA1 + ch] + b2f(ufS[q][wave + 1][w + 1]);
        float hv = b2f(x1g[idx]) * x2;
        h_bf[(size_t)p * 96 + ch] = f2b(hv);
    }
}

// ---------------- finalm: softmax(Sp)+ca in-block; v-tile LDS stage; kproj-MFMA + S@v + mproj-MFMA + residual. grid 256 x 256 ----------------
__global__ void __launch_bounds__(256) k_finalm(const void* __restrict__ x, const uint32_t* __restrict__ n1w_raw,
                        const ushortT* __restrict__ h_bf, const ushortT* __restrict__ Wkp,
                        const ushortT* __restrict__ Wmp, const ushortT* __restrict__ qkv,
                        const float* __restrict__ Sp, const float* __restrict__ gap,
                        const float* __restrict__ wts, void* __restrict__ out) {
    int fl = dtype_bf16(n1w_raw);
    int wave = threadIdx.x >> 6, lane = threadIdx.x & 63;
    int m = lane & 15, q = lane >> 4;
    int p = blockIdx.x * 64 + wave * 16 + m;
    int hw = p & 4095;
    int wl = wave * 16 + m;            // within-block pixel 0..63
    int bblk = (blockIdx.x * 64) >> 12;
    int hw0 = (blockIdx.x * 64) & 4095;

    __shared__ float sm[384];
    __shared__ float S_l[288];
    __shared__ float caL[96];
    __shared__ ushortT vS[48 * 68];    // v-tile, stride 68 to spread banks

    // stage v-tile: 48 channels x 64 pixels, coalesced rows
    for (int i2 = threadIdx.x; i2 < 48 * 64; i2 += 256) {
        int ch = i2 >> 6, w2 = i2 & 63;
        vS[ch * 68 + w2] = qkv[(size_t)(bblk * 144 + 96 + ch) * HW + hw0 + w2];
    }
    for (int i = threadIdx.x; i < 384; i += 256) {
        int hd = i / 48, k = i % 48;
        int bh = bblk * HEADS + hd;
        sm[i] = Sp[(bh * 2 + 0) * 48 + k] + Sp[(bh * 2 + 1) * 48 + k];
    }
    __syncthreads();
    if (threadIdx.x < 48) {
        int hd = threadIdx.x / 6, c = threadIdx.x % 6;
        const float* base = sm + hd * 48;
        float rqv = 1.f / fmaxf(sqrtf(base[36 + c]), 1e-12f);
        float tmp = wts[W_TEMP + hd];
        float row[CPH];
        #pragma unroll
        for (int d = 0; d < CPH; d++) {
            float rkv = 1.f / fmaxf(sqrtf(base[42 + d]), 1e-12f);
            row[d] = base[c * CPH + d] * rqv * rkv * tmp;
        }
        float mx = row[0];
        #pragma unroll
        for (int d = 1; d < CPH; d++) mx = fmaxf(mx, row[d]);
        float sum = 0.f;
        #pragma unroll
        for (int d = 0; d < CPH; d++) { row[d] = expf(row[d] - mx); sum += row[d]; }
        float inv = 1.f / sum;
        #pragma unroll
        for (int d = 0; d < CPH; d++) S_l[hd * 36 + c * CPH + d] = row[d] * inv;
    }
    if (threadIdx.x >= 64 && threadIdx.x < 160) {
        int i = threadIdx.x - 64;
        int which = i / 48, co = i % 48;
        const float* g = gap + bblk * Cc;
        float sacc = wts[(which ? W_CA2B : W_CA1B) + co];
        #pragma unroll
        for (int c = 0; c < Cc; c++)
            sacc += wts[(which ? W_CA2W : W_CA1W) + co * Cc + c] * g[c];
        caL[i] = sacc;
    }
    __syncthreads();

    // kproj: Dk = Wkp @ h_bf[p]
    short8 H0 = *(const short8*)(h_bf + (size_t)p * 96 + q * 8);
    short8 H1 = *(const short8*)(h_bf + (size_t)p * 96 + 32 + q * 8);
    short8 H2 = *(const short8*)(h_bf + (size_t)p * 96 + 64 + q * 8);
    f32x4 Dk[3];
    #pragma unroll
    for (int t = 0; t < 3; t++) {
        short8 A0 = *(const short8*)(Wkp + (16 * t + m) * 96 + q * 8);
        short8 A1 = *(const short8*)(Wkp + (16 * t + m) * 96 + 32 + q * 8);
        short8 A2 = *(const short8*)(Wkp + (16 * t + m) * 96 + 64 + q * 8);
        f32x4 z = {0.f, 0.f, 0.f, 0.f};
        f32x4 D = __builtin_amdgcn_mfma_f32_16x16x32_bf16(A0, H0, z, 0, 0, 0);
        D = __builtin_amdgcn_mfma_f32_16x16x32_bf16(A1, H1, D, 0, 0, 0);
        Dk[t] = __builtin_amdgcn_mfma_f32_16x16x32_bf16(A2, H2, D, 0, 0, 0);
    }

    // mdta B-fragments via S@v for this pixel (v from LDS)
    short8 Bm0, Bm1;
    #pragma unroll
    for (int jj = 0; jj < 8; jj++) {
        int c0 = q * 8 + jj;
        int hd0 = c0 / 6, cc0 = c0 - 6 * hd0;
        float a = 0.f;
        #pragma unroll
        for (int d = 0; d < CPH; d++)
            a += S_l[hd0 * 36 + cc0 * 6 + d] * b2f(vS[(hd0 * 6 + d) * 68 + wl]);
        Bm0[jj] = (short)f2b(a);
        int c1 = 32 + q * 8 + jj;
        float bv = 0.f;
        if (c1 < 48) {
            int hd1 = c1 / 6, cc1 = c1 - 6 * hd1;
            #pragma unroll
            for (int d = 0; d < CPH; d++)
                bv += S_l[hd1 * 36 + cc1 * 6 + d] * b2f(vS[(hd1 * 6 + d) * 68 + wl]);
        }
        Bm1[jj] = (short)f2b(bv);
    }

    // mproj + epilogue
    #pragma unroll
    for (int t = 0; t < 3; t++) {
        short8 A0 = *(const short8*)(Wmp + (16 * t + m) * 64 + q * 8);
        short8 A1 = *(const short8*)(Wmp + (16 * t + m) * 64 + 32 + q * 8);
        f32x4 z = {0.f, 0.f, 0.f, 0.f};
        f32x4 D = __builtin_amdgcn_mfma_f32_16x16x32_bf16(A0, Bm0, z, 0, 0, 0);
        D = __builtin_amdgcn_mfma_f32_16x16x32_bf16(A1, Bm1, D, 0, 0, 0);
        #pragma unroll
        for (int g = 0; g < 4; g++) {
            int co = 16 * t + 4 * q + g;
            int idx = (bblk * Cc + co) * HW + hw;
            float xv = fl ? b2f(((const ushortT*)x)[idx]) : ((const float*)x)[idx];
            float res = xv + Dk[t][g] * caL[co] + D[g] * caL[48 + co];
            if (fl) ((ushortT*)out)[idx] = f2b(res);
            else    ((float*)out)[idx] = res;
        }
    }
}

// ---------------- host launch ----------------
extern "C" void kernel_launch(void* const* d_in, const int* in_sizes, int n_in,
                              void* d_out, int out_size, void* d_ws, size_t ws_size,
                              hipStream_t stream) {
    float* ws_f = (float*)d_ws;

    ushortT* bufA  = (ushortT*)(ws_f + FA);     // t1 bf16
    ushortT* bufB  = (ushortT*)(ws_f + FB);     // t2 bf16
    ushortT* x1g   = (ushortT*)(ws_f + FC);
    ushortT* uf    = (ushortT*)(ws_f + FD);
    ushortT* araw  = (ushortT*)(ws_f + FARAW);
    ushortT* attn_t= (ushortT*)(ws_f + FATT);
    float* gap   = ws_f + FGAP;
    float* Sp    = ws_f + FSP;
    float* wts   = ws_f + FW;
    ushortT* att_bf  = (ushortT*)(ws_f + FATTB);
    ushortT* Wt      = (ushortT*)(ws_f + FWT);
    float2* stats    = (float2*)(ws_f + FSTAT);
    ushortT* h_bf    = (ushortT*)(ws_f + FHBF);
    ushortT* Wpw     = (ushortT*)(ws_f + FWPW);
    ushortT* Wqk     = (ushortT*)(ws_f + FWQK);
    ushortT* Wkp     = (ushortT*)(ws_f + FWKP);
    ushortT* Wmp     = (ushortT*)(ws_f + FWMP);
    ushortT* qkvr    = (ushortT*)(ws_f + FQKVR);
    ushortT* qkv     = (ushortT*)(ws_f + FQKV);

    const uint32_t* n1w_raw = (const uint32_t*)d_in[1];

    static const int wsizes[27] = {48,48,48,48,4608,864,4608,864,4608,432,24,384,32,
                                   1536,32,110592,3072,32,96,8,6912,1296,2304,2304,48,2304,48};
    static const int woffs[27] = {W_N1W,W_N1B,W_N2W,W_N2B,W_KDW1,W_KDW2,W_KC1A,W_KC1B,
                                  W_KPROJ,W_C2AW,W_C2AB,W_C2BW,W_C2BB,W_C211W,W_C211B,
                                  W_KW,W_KB,W_ATTG,W_GA1,W_TEMP,W_QKVW,W_QKVDW,W_MPROJ,
                                  W_CA1W,W_CA1B,W_CA2W,W_CA2B};
    ConvPack cp;
    int acc = 0;
    for (int i = 0; i < 27; i++) {
        cp.src[i] = d_in[i + 1];
        cp.dstoff[i] = woffs[i];
        cp.pre[i] = acc;
        acc += wsizes[i];
    }
    cp.pre[27] = acc;
    RawW rw;
    rw.kdw1 = d_in[5]; rw.kc1a = d_in[7]; rw.c211w = d_in[14]; rw.qkvw = d_in[21];
    rw.kproj = d_in[9]; rw.mproj = d_in[23]; rw.kw = d_in[16]; rw.kb = d_in[17];
    rw.n1w = d_in[1]; rw.n1b = d_in[2]; rw.n2w = d_in[3]; rw.n2b = d_in[4];

    k_prep<<<dim3(64, 8), 256, 0, stream>>>(cp, rw, wts, Wt, Wpw, Wqk, Wkp, Wmp,
                                            d_in[0], gap, stats, n1w_raw);
    k_pw1m<<<dim3(896), 256, 0, stream>>>(d_in[0], stats, Wpw, Wqk, rw, wts,
                                          bufA, bufB, attn_t, qkvr, araw, n1w_raw);
    k_dw<<<dim3(8, 344), 256, 0, stream>>>(bufA, bufB, qkvr, araw, attn_t, wts,
                                           x1g, uf, qkv, att_bf);
    k_kba<<<dim3(64, 25), 256, 0, stream>>>(att_bf, uf, x1g, Wt, qkv, wts, h_bf, Sp);
    k_finalm<<<dim3(256), 256, 0, stream>>>(d_in[0], n1w_raw, h_bf, Wkp, Wmp,
                                            qkv, Sp, gap, wts, d_out);
}